// Round 1
// 859.771 us; speedup vs baseline: 1.2122x; 1.2122x over previous
//
#include <hip/hip_runtime.h>

#define N_USER 50000
#define N_ITEM 30000
#define DIM    64
#define NTOT   80000
#define NNZ_UI 1000000
#define NNZ_R  800000
#define NNZ_II 300000
#define IMG_F  512
#define TXT_F  384

#define NROWS_ALL 190000            // NTOT + N_USER + N_ITEM + N_ITEM
#define NNZ_ALL   2400000           // NNZ_UI + NNZ_R + 2*NNZ_II
#define BASE_R    NTOT              // 80000
#define BASE_II   (NTOT + N_USER)   // 130000
#define BASE_IT   (NTOT + N_USER + N_ITEM) // 160000

// row-bucketed CSR build: 512 rows per bucket
#define RB_BITS   9
#define RB_ROWS   512
#define NBUCK     ((NROWS_ALL + RB_ROWS - 1) / RB_ROWS)   // 372
#define NBLK_A2   400
#define EDG_A2    6000              // 400 * 6000 == NNZ_ALL exactly

// ---------------- edge decode helpers (fused 4-list view) ----------------
__device__ __forceinline__ int edge_row(int i,
        const int* __restrict__ r0, const int* __restrict__ r1,
        const int* __restrict__ r2, const int* __restrict__ r3){
    if (i < NNZ_UI)                       return r0[i];
    if (i < NNZ_UI + NNZ_R)               return BASE_R  + r1[i - NNZ_UI];
    if (i < NNZ_UI + NNZ_R + NNZ_II)      return BASE_II + r2[i - NNZ_UI - NNZ_R];
    return BASE_IT + r3[i - NNZ_UI - NNZ_R - NNZ_II];
}

__device__ __forceinline__ void edge_all(int i,
        const int* __restrict__ r0, const int* __restrict__ c0, const float* __restrict__ v0,
        const int* __restrict__ r1, const int* __restrict__ c1, const float* __restrict__ v1,
        const int* __restrict__ r2, const int* __restrict__ c2, const float* __restrict__ v2,
        const int* __restrict__ r3, const int* __restrict__ c3, const float* __restrict__ v3,
        int& gr, int& col, float& val){
    if (i < NNZ_UI){
        gr = r0[i]; col = c0[i]; val = v0[i];
    } else if (i < NNZ_UI + NNZ_R){
        int j = i - NNZ_UI;               gr = BASE_R  + r1[j]; col = c1[j]; val = v1[j];
    } else if (i < NNZ_UI + NNZ_R + NNZ_II){
        int j = i - NNZ_UI - NNZ_R;       gr = BASE_II + r2[j]; col = c2[j]; val = v2[j];
    } else {
        int j = i - NNZ_UI - NNZ_R - NNZ_II; gr = BASE_IT + r3[j]; col = c3[j]; val = v3[j];
    }
}

// ---------------- build 1: bucket histogram (LDS-aggregated) ----------------
__global__ __launch_bounds__(256) void k_bhist(const int* __restrict__ r0,
        const int* __restrict__ r1, const int* __restrict__ r2,
        const int* __restrict__ r3, int* __restrict__ bcnt){
    __shared__ int h[NBUCK];
    for (int i = threadIdx.x; i < NBUCK; i += 256) h[i] = 0;
    __syncthreads();
    const int stride = gridDim.x * 256;
    for (int i = blockIdx.x * 256 + threadIdx.x; i < NNZ_ALL; i += stride){
        int gr = edge_row(i, r0, r1, r2, r3);
        atomicAdd(&h[gr >> RB_BITS], 1);
    }
    __syncthreads();
    for (int i = threadIdx.x; i < NBUCK; i += 256){
        int c = h[i];
        if (c) atomicAdd(&bcnt[i], c);
    }
}

// ---------------- build 2: scan bucket counts (single block) ----------------
__global__ __launch_bounds__(512) void k_bscan(const int* __restrict__ bcnt,
        int* __restrict__ bbase, int* __restrict__ off){
    __shared__ int sh[512];
    const int t = threadIdx.x;
    int v = (t < NBUCK) ? bcnt[t] : 0;
    sh[t] = v;
    __syncthreads();
    for (int d = 1; d < 512; d <<= 1){
        int u = (t >= d) ? sh[t - d] : 0;
        __syncthreads();
        sh[t] += u;
        __syncthreads();
    }
    if (t < NBUCK) bbase[t] = sh[t] - v;          // exclusive prefix
    if (t == NBUCK - 1){
        bbase[NBUCK] = sh[t];                      // grand total (== NNZ_ALL)
        off[NROWS_ALL] = sh[t];
    }
}

// ---------------- build 3: bin edges into bucket-major staging ----------------
// rec.x = (col << 9) | (gr & 511), rec.y = bits(val). col < 2^17, so fits.
__global__ __launch_bounds__(256) void k_bin(
        const int* __restrict__ r0, const int* __restrict__ c0, const float* __restrict__ v0,
        const int* __restrict__ r1, const int* __restrict__ c1, const float* __restrict__ v1,
        const int* __restrict__ r2, const int* __restrict__ c2, const float* __restrict__ v2,
        const int* __restrict__ r3, const int* __restrict__ c3, const float* __restrict__ v3,
        const int* __restrict__ bbase, int* __restrict__ bcur,
        int2* __restrict__ binned){
    __shared__ int lofs[NBUCK];
    __shared__ int lcur[NBUCK];
    const int t = threadIdx.x;
    for (int i = t; i < NBUCK; i += 256){ lofs[i] = 0; lcur[i] = 0; }
    __syncthreads();
    const int s0 = blockIdx.x * EDG_A2, s1 = s0 + EDG_A2;
    // pass 1: local bucket histogram
    for (int i = s0 + t; i < s1; i += 256){
        int gr = edge_row(i, r0, r1, r2, r3);
        atomicAdd(&lofs[gr >> RB_BITS], 1);
    }
    __syncthreads();
    // reserve per-bucket chunks (one global atomic per (block,bucket))
    for (int i = t; i < NBUCK; i += 256){
        int c = lofs[i];
        lofs[i] = c ? (bbase[i] + atomicAdd(&bcur[i], c)) : 0;
    }
    __syncthreads();
    // pass 2: write packed records into this block's chunks
    for (int i = s0 + t; i < s1; i += 256){
        int gr, col; float val;
        edge_all(i, r0, c0, v0, r1, c1, v1, r2, c2, v2, r3, c3, v3, gr, col, val);
        int b = gr >> RB_BITS;
        int slot = atomicAdd(&lcur[b], 1);
        binned[lofs[b] + slot] = make_int2((col << RB_BITS) | (gr & (RB_ROWS - 1)),
                                           __float_as_int(val));
    }
}

// ---------------- build 4: per-bucket hist+scan+scatter (one block = one bucket)
// Produces off[] for the bucket's 512 rows and writes csr into a private
// ~60 KB window -> full-line writebacks from a single CU's L2.
__global__ __launch_bounds__(256) void k_scatter(const int* __restrict__ bbase,
        const int2* __restrict__ binned, int* __restrict__ off,
        int2* __restrict__ csr){
    __shared__ int h[RB_ROWS];
    const int t = threadIdx.x;
    const int b = blockIdx.x;
    const int base = bbase[b];
    const int nb = bbase[b + 1] - base;
    h[t] = 0; h[t + 256] = 0;
    __syncthreads();
    // local row histogram
    for (int i = t; i < nb; i += 256)
        atomicAdd(&h[binned[base + i].x & (RB_ROWS - 1)], 1);
    __syncthreads();
    // exclusive scan of 512 counters by wave 0 (8 elems/lane + shfl scan)
    if (t < 64){
        int v[8], s = 0;
#pragma unroll
        for (int k = 0; k < 8; ++k){ v[k] = h[t * 8 + k]; s += v[k]; }
        int incl = s;
#pragma unroll
        for (int d = 1; d < 64; d <<= 1){
            int u = __shfl_up(incl, d, 64);
            if (t >= d) incl += u;
        }
        int run = incl - s;
#pragma unroll
        for (int k = 0; k < 8; ++k){ int tmp = v[k]; h[t * 8 + k] = run; run += tmp; }
    }
    __syncthreads();
    // emit row offsets
    const int row0 = b << RB_BITS;
    for (int i = t; i < RB_ROWS; i += 256){
        int r = row0 + i;
        if (r < NROWS_ALL) off[r] = base + h[i];
    }
    __syncthreads();
    // scatter into private CSR window; h[] doubles as row cursors
    for (int i = t; i < nb; i += 256){
        int2 rec = binned[base + i];
        int lr = rec.x & (RB_ROWS - 1);
        int slot = atomicAdd(&h[lr], 1);
        csr[base + slot] = make_int2(rec.x >> RB_BITS, rec.y);
    }
}

// ---------------- cat0 = [item_emb; user_emb] ----------------
__global__ void k_cat0(const float* __restrict__ item, const float* __restrict__ user,
                       float* __restrict__ o1){
    int i = blockIdx.x * 256 + threadIdx.x;
    const int ITEMS = N_ITEM * DIM;
    o1[i] = (i < ITEMS) ? item[i] : user[i - ITEMS];
}

// ---------------- pull-SpMM: y[r] = sum val*x[col], one row per 16 lanes ----------------
__global__ void k_pull(const int* __restrict__ off, const int2* __restrict__ csr,
                       const float* __restrict__ x, float* __restrict__ y, int nrows){
    int t = blockIdx.x * 256 + threadIdx.x;
    int r = t >> 4;
    if (r >= nrows) return;
    int l = (t & 15) << 2;
    int s = off[r], e = off[r + 1];
    float4 acc = {0.f, 0.f, 0.f, 0.f};
    for (int j = s; j < e; ++j){
        int2 ed = csr[j];
        float v = __int_as_float(ed.y);
        const float4 xv = *reinterpret_cast<const float4*>(x + ((long)ed.x << 6) + l);
        acc.x = fmaf(v, xv.x, acc.x);
        acc.y = fmaf(v, xv.y, acc.y);
        acc.z = fmaf(v, xv.z, acc.z);
        acc.w = fmaf(v, xv.w, acc.w);
    }
    *reinterpret_cast<float4*>(y + ((long)r << 6) + l) = acc;
}

// ---------------- content = (cat0+cat1+cat2)/3 ----------------
__global__ void k_content(const float* __restrict__ a, const float* __restrict__ b,
                          const float* __restrict__ c, float* __restrict__ o0){
    int i = blockIdx.x * 256 + threadIdx.x;
    o0[i] = (a[i] + b[i] + c[i]) * (1.0f / 3.0f);
}

// ---------------- projection: leaky(BN(X @ W + b)) ----------------
template<int K>
__global__ __launch_bounds__(512) void k_proj(const float* __restrict__ X,
        const float* __restrict__ W, const float* __restrict__ b,
        const float* __restrict__ g, const float* __restrict__ beta,
        float* __restrict__ out){
    __shared__ float xs[8 * K];
    const int t = threadIdx.x;
    const int row0 = blockIdx.x * 8;
    const float4* src4 = reinterpret_cast<const float4*>(X + (long)row0 * K);
    float4* xs4 = reinterpret_cast<float4*>(xs);
#pragma unroll
    for (int i = t; i < 2 * K; i += 512) xs4[i] = src4[i];
    __syncthreads();
    const int r = t >> 6, c = t & 63;
    const float* xr = xs + r * K;
    float acc = 0.f;
#pragma unroll 8
    for (int k = 0; k < K; ++k) acc = fmaf(xr[k], W[k * 64 + c], acc);
    float h = acc + b[c];
    h = h * (g[c] * 0.99999500003749943f) + beta[c];   // g / sqrt(1 + 1e-5)
    out[(long)(row0 + r) * 64 + c] = (h >= 0.f) ? h : 0.01f * h;
}

// ---------------- gate: it = item_emb * sigmoid(feat @ Wg + bg) ----------------
__global__ __launch_bounds__(512) void k_gate(const float* __restrict__ feat,
        const float* __restrict__ Wg, const float* __restrict__ bg,
        const float* __restrict__ item, float* __restrict__ it){
    __shared__ float fs[8][64];
    const int t = threadIdx.x;
    const int row0 = blockIdx.x * 8;
    fs[t >> 6][t & 63] = feat[(long)row0 * 64 + t];
    __syncthreads();
    const int r = t >> 6, c = t & 63;
    float acc = 0.f;
#pragma unroll
    for (int k = 0; k < 64; ++k) acc = fmaf(fs[r][k], Wg[k * 64 + c], acc);
    acc += bg[c];
    float sg = 1.f / (1.f + __expf(-acc));
    long idx = (long)(row0 + r) * 64 + c;
    it[idx] = item[idx] * sg;
}

// ---------------- copy ID elements ----------------
__global__ void k_copy(const float* __restrict__ s, float* __restrict__ d){
    int i = blockIdx.x * 256 + threadIdx.x;
    d[i] = s[i];
}

// ---------------- attention fusion; reads o1/o2, rewrites o1/o2/o3 in place ----------------
__global__ __launch_bounds__(256) void k_fuse(const float* __restrict__ img,
        const float* __restrict__ txt, const float* __restrict__ W1,
        const float* __restrict__ b1, const float* __restrict__ w2,
        float* __restrict__ out){
    __shared__ float si[4][64], st[4][64];
    const int t = threadIdx.x;
    const int w = t >> 6, c = t & 63;
    const long row = (long)blockIdx.x * 4 + w;
    float ie = img[row * 64 + c];
    float te = txt[row * 64 + c];
    si[w][c] = ie;  st[w][c] = te;
    __syncthreads();
    float ai = 0.f, at = 0.f;
#pragma unroll
    for (int k = 0; k < 64; ++k){
        float wv = W1[k * 64 + c];
        ai = fmaf(si[w][k], wv, ai);
        at = fmaf(st[w][k], wv, at);
    }
    float bb = b1[c];
    float hi = ai + bb; hi = (hi >= 0.f) ? hi : 0.01f * hi;
    float ht = at + bb; ht = (ht >= 0.f) ? ht : 0.01f * ht;
    float wc = w2[c];
    float pi = hi * wc, pt = ht * wc;
#pragma unroll
    for (int m = 1; m < 64; m <<= 1){
        pi += __shfl_xor(pi, m, 64);
        pt += __shfl_xor(pt, m, 64);
    }
    float mx = fmaxf(pi, pt);
    float ei = __expf(pi - mx), et = __expf(pt - mx);
    float inv = 1.f / (ei + et);
    float wi = ei * inv, wt = et * inv;
    float common = wi * ie + wt * te;
    const long NTD = (long)NTOT * DIM;
    long o = row * 64 + c;
    out[NTD + o]     = ie - common;
    out[2 * NTD + o] = te - common;
    out[3 * NTD + o] = common;
}

extern "C" void kernel_launch(void* const* d_in, const int* in_sizes, int n_in,
                              void* d_out, int out_size, void* d_ws, size_t ws_size,
                              hipStream_t stream){
    const float* user_emb  = (const float*)d_in[0];
    const float* item_emb  = (const float*)d_in[1];
    const float* image_emb = (const float*)d_in[2];
    const float* text_emb  = (const float*)d_in[3];
    const float* W_img = (const float*)d_in[4];
    const float* b_img = (const float*)d_in[5];
    const float* g_img = (const float*)d_in[6];
    const float* be_img= (const float*)d_in[7];
    const float* W_txt = (const float*)d_in[8];
    const float* b_txt = (const float*)d_in[9];
    const float* g_txt = (const float*)d_in[10];
    const float* be_txt= (const float*)d_in[11];
    const float* W_gi  = (const float*)d_in[12];
    const float* b_gi  = (const float*)d_in[13];
    const float* W_gt  = (const float*)d_in[14];
    const float* b_gt  = (const float*)d_in[15];
    const float* W_c1  = (const float*)d_in[16];
    const float* b_c1  = (const float*)d_in[17];
    const float* w_c2  = (const float*)d_in[18];
    const float* ui_vals = (const float*)d_in[19];
    const float* R_vals  = (const float*)d_in[20];
    const float* ii_iv   = (const float*)d_in[21];
    const float* ii_tv   = (const float*)d_in[22];
    const int* ui_rows = (const int*)d_in[23];
    const int* ui_cols = (const int*)d_in[24];
    const int* R_rows  = (const int*)d_in[25];
    const int* R_cols  = (const int*)d_in[26];
    const int* ii_ir   = (const int*)d_in[27];
    const int* ii_ic   = (const int*)d_in[28];
    const int* ii_tr   = (const int*)d_in[29];
    const int* ii_tc   = (const int*)d_in[30];

    const long ND = (long)NTOT * DIM;    // 5,120,000
    const long ID = (long)N_ITEM * DIM;  // 1,920,000
    const long UD = (long)N_USER * DIM;  // 3,200,000

    float* out = (float*)d_out;
    float* o0 = out;
    float* o1 = out + ND;
    float* o2 = out + 2 * ND;
    float* o3 = out + 3 * ND;

    // P/Q scratch live in o3 (free until k_fuse): 2*ID <= ND
    float* P = o3;
    float* Q = o3 + ID;

    // binned staging (19.2 MB) lives in o0 — dead until k_content at the
    // end of the content branch, long after the CSR build completes.
    int2* binned = (int2*)o0;

    // ---- workspace (~20 MB): combined CSR + bucket tables ----
    int2* csr   = (int2*)d_ws;                  // NNZ_ALL (19.2 MB)
    int*  off   = (int*)(csr + NNZ_ALL);        // NROWS_ALL + 1 (+pad)
    int*  bcnt  = off + NROWS_ALL + 4;          // NBUCK
    int*  bcur  = bcnt + NBUCK;                 // NBUCK (adjacent: one memset)
    int*  bbase = bcur + NBUCK;                 // NBUCK + 1

    // ---- build combined CSR: bucket-hist -> scan -> bin -> per-bucket scatter
    hipMemsetAsync(bcnt, 0, 2 * NBUCK * sizeof(int), stream);   // bcnt + bcur
    k_bhist<<<512, 256, 0, stream>>>(ui_rows, R_rows, ii_ir, ii_tr, bcnt);
    k_bscan<<<1, 512, 0, stream>>>(bcnt, bbase, off);
    k_bin<<<NBLK_A2, 256, 0, stream>>>(
        ui_rows, ui_cols, ui_vals,  R_rows, R_cols, R_vals,
        ii_ir, ii_ic, ii_iv,        ii_tr, ii_tc, ii_tv,
        bbase, bcur, binned);
    k_scatter<<<NBUCK, 256, 0, stream>>>(bbase, binned, off, csr);

    const int* offUI = off;
    const int* offR  = off + BASE_R;
    const int* offI2 = off + BASE_II;
    const int* offT2 = off + BASE_IT;

    // ---- content branch ----
    k_cat0<<<ND / 256, 256, 0, stream>>>(item_emb, user_emb, o1);
    k_pull<<<NTOT / 16, 256, 0, stream>>>(offUI, csr, o1, o2, NTOT);
    k_pull<<<NTOT / 16, 256, 0, stream>>>(offUI, csr, o2, o3, NTOT);
    k_content<<<ND / 256, 256, 0, stream>>>(o1, o2, o3, o0);
    // o0 (binned) overwritten only here; o3 (P/Q scratch) free again from here

    // ---- image branch -> o1 ----
    k_proj<IMG_F><<<N_ITEM / 8, 512, 0, stream>>>(image_emb, W_img, b_img, g_img, be_img, Q);
    k_gate<<<N_ITEM / 8, 512, 0, stream>>>(Q, W_gi, b_gi, item_emb, P);
    k_pull<<<N_ITEM / 16, 256, 0, stream>>>(offI2, csr, P, Q, N_ITEM);
    k_pull<<<N_ITEM / 16, 256, 0, stream>>>(offI2, csr, Q, P, N_ITEM);
    k_pull<<<N_USER / 16, 256, 0, stream>>>(offR, csr, P, o1, N_USER);
    k_copy<<<ID / 256, 256, 0, stream>>>(P, o1 + UD);

    // ---- text branch -> o2 ----
    k_proj<TXT_F><<<N_ITEM / 8, 512, 0, stream>>>(text_emb, W_txt, b_txt, g_txt, be_txt, Q);
    k_gate<<<N_ITEM / 8, 512, 0, stream>>>(Q, W_gt, b_gt, item_emb, P);
    k_pull<<<N_ITEM / 16, 256, 0, stream>>>(offT2, csr, P, Q, N_ITEM);
    k_pull<<<N_ITEM / 16, 256, 0, stream>>>(offT2, csr, Q, P, N_ITEM);
    k_pull<<<N_USER / 16, 256, 0, stream>>>(offR, csr, P, o2, N_USER);
    k_copy<<<ID / 256, 256, 0, stream>>>(P, o2 + UD);

    // ---- fusion epilogue (in-place on o1/o2, writes o3) ----
    k_fuse<<<NTOT / 4, 256, 0, stream>>>(o1, o2, W_c1, b_c1, w_c2, out);
}

// Round 2
// 636.742 us; speedup vs baseline: 1.6368x; 1.3503x over previous
//
#include <hip/hip_runtime.h>

#define N_USER 50000
#define N_ITEM 30000
#define DIM    64
#define NTOT   80000
#define NNZ_UI 1000000
#define NNZ_R  800000
#define NNZ_II 300000
#define IMG_F  512
#define TXT_F  384

#define NROWS_ALL 190000            // NTOT + N_USER + N_ITEM + N_ITEM
#define NNZ_ALL   2400000           // NNZ_UI + NNZ_R + 2*NNZ_II
#define BASE_R    NTOT              // 80000
#define BASE_II   (NTOT + N_USER)   // 130000
#define BASE_IT   (NTOT + N_USER + N_ITEM) // 160000

// row-bucketed CSR build: 512 rows per bucket
#define RB_BITS   9
#define RB_ROWS   512
#define NBUCK     ((NROWS_ALL + RB_ROWS - 1) / RB_ROWS)   // 372
#define NBLK_A2   400
#define EDG_A2    6000              // 400 * 6000 == NNZ_ALL exactly

// ---------------- edge decode helpers (fused 4-list view) ----------------
__device__ __forceinline__ int edge_row(int i,
        const int* __restrict__ r0, const int* __restrict__ r1,
        const int* __restrict__ r2, const int* __restrict__ r3){
    if (i < NNZ_UI)                       return r0[i];
    if (i < NNZ_UI + NNZ_R)               return BASE_R  + r1[i - NNZ_UI];
    if (i < NNZ_UI + NNZ_R + NNZ_II)      return BASE_II + r2[i - NNZ_UI - NNZ_R];
    return BASE_IT + r3[i - NNZ_UI - NNZ_R - NNZ_II];
}

__device__ __forceinline__ void edge_all(int i,
        const int* __restrict__ r0, const int* __restrict__ c0, const float* __restrict__ v0,
        const int* __restrict__ r1, const int* __restrict__ c1, const float* __restrict__ v1,
        const int* __restrict__ r2, const int* __restrict__ c2, const float* __restrict__ v2,
        const int* __restrict__ r3, const int* __restrict__ c3, const float* __restrict__ v3,
        int& gr, int& col, float& val){
    if (i < NNZ_UI){
        gr = r0[i]; col = c0[i]; val = v0[i];
    } else if (i < NNZ_UI + NNZ_R){
        int j = i - NNZ_UI;               gr = BASE_R  + r1[j]; col = c1[j]; val = v1[j];
    } else if (i < NNZ_UI + NNZ_R + NNZ_II){
        int j = i - NNZ_UI - NNZ_R;       gr = BASE_II + r2[j]; col = c2[j]; val = v2[j];
    } else {
        int j = i - NNZ_UI - NNZ_R - NNZ_II; gr = BASE_IT + r3[j]; col = c3[j]; val = v3[j];
    }
}

// ---------------- build 1: bucket histogram (LDS-aggregated) ----------------
__global__ __launch_bounds__(256) void k_bhist(const int* __restrict__ r0,
        const int* __restrict__ r1, const int* __restrict__ r2,
        const int* __restrict__ r3, int* __restrict__ bcnt){
    __shared__ int h[NBUCK];
    for (int i = threadIdx.x; i < NBUCK; i += 256) h[i] = 0;
    __syncthreads();
    const int stride = gridDim.x * 256;
    for (int i = blockIdx.x * 256 + threadIdx.x; i < NNZ_ALL; i += stride){
        int gr = edge_row(i, r0, r1, r2, r3);
        atomicAdd(&h[gr >> RB_BITS], 1);
    }
    __syncthreads();
    for (int i = threadIdx.x; i < NBUCK; i += 256){
        int c = h[i];
        if (c) atomicAdd(&bcnt[i], c);
    }
}

// ---------------- build 2: scan bucket counts (single block) ----------------
__global__ __launch_bounds__(512) void k_bscan(const int* __restrict__ bcnt,
        int* __restrict__ bbase, int* __restrict__ off){
    __shared__ int sh[512];
    const int t = threadIdx.x;
    int v = (t < NBUCK) ? bcnt[t] : 0;
    sh[t] = v;
    __syncthreads();
    for (int d = 1; d < 512; d <<= 1){
        int u = (t >= d) ? sh[t - d] : 0;
        __syncthreads();
        sh[t] += u;
        __syncthreads();
    }
    if (t < NBUCK) bbase[t] = sh[t] - v;          // exclusive prefix
    if (t == NBUCK - 1){
        bbase[NBUCK] = sh[t];                      // grand total (== NNZ_ALL)
        off[NROWS_ALL] = sh[t];
    }
}

// ---------------- build 3: bin edges into bucket-major staging ----------------
// rec.x = (col << 9) | (gr & 511), rec.y = bits(val). col < 2^17, so fits.
__global__ __launch_bounds__(256) void k_bin(
        const int* __restrict__ r0, const int* __restrict__ c0, const float* __restrict__ v0,
        const int* __restrict__ r1, const int* __restrict__ c1, const float* __restrict__ v1,
        const int* __restrict__ r2, const int* __restrict__ c2, const float* __restrict__ v2,
        const int* __restrict__ r3, const int* __restrict__ c3, const float* __restrict__ v3,
        const int* __restrict__ bbase, int* __restrict__ bcur,
        int2* __restrict__ binned){
    __shared__ int lofs[NBUCK];
    __shared__ int lcur[NBUCK];
    const int t = threadIdx.x;
    for (int i = t; i < NBUCK; i += 256){ lofs[i] = 0; lcur[i] = 0; }
    __syncthreads();
    const int s0 = blockIdx.x * EDG_A2, s1 = s0 + EDG_A2;
    // pass 1: local bucket histogram
    for (int i = s0 + t; i < s1; i += 256){
        int gr = edge_row(i, r0, r1, r2, r3);
        atomicAdd(&lofs[gr >> RB_BITS], 1);
    }
    __syncthreads();
    // reserve per-bucket chunks (one global atomic per (block,bucket))
    for (int i = t; i < NBUCK; i += 256){
        int c = lofs[i];
        lofs[i] = c ? (bbase[i] + atomicAdd(&bcur[i], c)) : 0;
    }
    __syncthreads();
    // pass 2: write packed records into this block's chunks
    for (int i = s0 + t; i < s1; i += 256){
        int gr, col; float val;
        edge_all(i, r0, c0, v0, r1, c1, v1, r2, c2, v2, r3, c3, v3, gr, col, val);
        int b = gr >> RB_BITS;
        int slot = atomicAdd(&lcur[b], 1);
        binned[lofs[b] + slot] = make_int2((col << RB_BITS) | (gr & (RB_ROWS - 1)),
                                           __float_as_int(val));
    }
}

// ---------------- build 4: per-bucket hist+scan+scatter (one block = one bucket)
__global__ __launch_bounds__(256) void k_scatter(const int* __restrict__ bbase,
        const int2* __restrict__ binned, int* __restrict__ off,
        int2* __restrict__ csr){
    __shared__ int h[RB_ROWS];
    const int t = threadIdx.x;
    const int b = blockIdx.x;
    const int base = bbase[b];
    const int nb = bbase[b + 1] - base;
    h[t] = 0; h[t + 256] = 0;
    __syncthreads();
    // local row histogram
    for (int i = t; i < nb; i += 256)
        atomicAdd(&h[binned[base + i].x & (RB_ROWS - 1)], 1);
    __syncthreads();
    // exclusive scan of 512 counters by wave 0 (8 elems/lane + shfl scan)
    if (t < 64){
        int v[8], s = 0;
#pragma unroll
        for (int k = 0; k < 8; ++k){ v[k] = h[t * 8 + k]; s += v[k]; }
        int incl = s;
#pragma unroll
        for (int d = 1; d < 64; d <<= 1){
            int u = __shfl_up(incl, d, 64);
            if (t >= d) incl += u;
        }
        int run = incl - s;
#pragma unroll
        for (int k = 0; k < 8; ++k){ int tmp = v[k]; h[t * 8 + k] = run; run += tmp; }
    }
    __syncthreads();
    // emit row offsets
    const int row0 = b << RB_BITS;
    for (int i = t; i < RB_ROWS; i += 256){
        int r = row0 + i;
        if (r < NROWS_ALL) off[r] = base + h[i];
    }
    __syncthreads();
    // scatter into private CSR window; h[] doubles as row cursors
    for (int i = t; i < nb; i += 256){
        int2 rec = binned[base + i];
        int lr = rec.x & (RB_ROWS - 1);
        int slot = atomicAdd(&h[lr], 1);
        csr[base + slot] = make_int2(rec.x >> RB_BITS, rec.y);
    }
}

// ---------------- cat0 = [item_emb; user_emb] ----------------
__global__ void k_cat0(const float* __restrict__ item, const float* __restrict__ user,
                       float* __restrict__ o1){
    int i = blockIdx.x * 256 + threadIdx.x;
    const int ITEMS = N_ITEM * DIM;
    o1[i] = (i < ITEMS) ? item[i] : user[i - ITEMS];
}

// ---------------- pull-SpMM: y[r] = sum val*x[col], one row per 16 lanes ----------------
// 2-deep unroll: two independent gathers in flight per group.
__global__ void k_pull(const int* __restrict__ off, const int2* __restrict__ csr,
                       const float* __restrict__ x, float* __restrict__ y, int nrows){
    int t = blockIdx.x * 256 + threadIdx.x;
    int r = t >> 4;
    if (r >= nrows) return;
    int l = (t & 15) << 2;
    int s = off[r], e = off[r + 1];
    float4 a0 = {0.f, 0.f, 0.f, 0.f};
    float4 a1 = {0.f, 0.f, 0.f, 0.f};
    int j = s;
    for (; j + 2 <= e; j += 2){
        int2 e0 = csr[j];
        int2 e1 = csr[j + 1];
        float v0 = __int_as_float(e0.y);
        float v1 = __int_as_float(e1.y);
        const float4 x0 = *reinterpret_cast<const float4*>(x + ((long)e0.x << 6) + l);
        const float4 x1 = *reinterpret_cast<const float4*>(x + ((long)e1.x << 6) + l);
        a0.x = fmaf(v0, x0.x, a0.x);
        a0.y = fmaf(v0, x0.y, a0.y);
        a0.z = fmaf(v0, x0.z, a0.z);
        a0.w = fmaf(v0, x0.w, a0.w);
        a1.x = fmaf(v1, x1.x, a1.x);
        a1.y = fmaf(v1, x1.y, a1.y);
        a1.z = fmaf(v1, x1.z, a1.z);
        a1.w = fmaf(v1, x1.w, a1.w);
    }
    if (j < e){
        int2 e0 = csr[j];
        float v0 = __int_as_float(e0.y);
        const float4 x0 = *reinterpret_cast<const float4*>(x + ((long)e0.x << 6) + l);
        a0.x = fmaf(v0, x0.x, a0.x);
        a0.y = fmaf(v0, x0.y, a0.y);
        a0.z = fmaf(v0, x0.z, a0.z);
        a0.w = fmaf(v0, x0.w, a0.w);
    }
    a0.x += a1.x; a0.y += a1.y; a0.z += a1.z; a0.w += a1.w;
    *reinterpret_cast<float4*>(y + ((long)r << 6) + l) = a0;
}

// ---------------- content = (cat0+cat1+cat2)/3 ----------------
__global__ void k_content(const float* __restrict__ a, const float* __restrict__ b,
                          const float* __restrict__ c, float* __restrict__ o0){
    int i = blockIdx.x * 256 + threadIdx.x;
    o0[i] = (a[i] + b[i] + c[i]) * (1.0f / 3.0f);
}

// ---------------- fused projection + gate ----------------
// P = item_emb * sigmoid( leaky(BN(X@W + b)) @ Wg + bg )
// Register-tiled GEMM: 48 rows x 64 cols per 256-thread block.
// Thread (tr,tc) tr=t>>4, tc=t&15 owns rows {tr, tr+16, tr+32}, cols tc*4..+3.
template<int K>
__global__ __launch_bounds__(256) void k_projgate(
        const float* __restrict__ X,
        const float* __restrict__ W,  const float* __restrict__ b,
        const float* __restrict__ g,  const float* __restrict__ beta,
        const float* __restrict__ Wg, const float* __restrict__ bg,
        const float* __restrict__ item, float* __restrict__ outP){
    __shared__ float xs[48][68];    // +4 pad: a-frag reads conflict-free, f4-aligned
    __shared__ float ws[64][64];
    const int t  = threadIdx.x;
    const int tr = t >> 4;          // 0..15
    const int tc = t & 15;          // 0..15
    const int row0 = blockIdx.x * 48;

    float acc[3][4];
#pragma unroll
    for (int i = 0; i < 3; ++i)
#pragma unroll
        for (int j = 0; j < 4; ++j) acc[i][j] = 0.f;

    for (int ks = 0; ks < K; ks += 64){
        __syncthreads();
        // stage X tile [48][64]
#pragma unroll
        for (int i = 0; i < 3; ++i){
            int r = tr + 16 * i;
            *reinterpret_cast<float4*>(&xs[r][tc * 4]) =
                *reinterpret_cast<const float4*>(X + (long)(row0 + r) * K + ks + tc * 4);
        }
        // stage W tile [64][64] (contiguous 16 KB)
        {
            const float4* wsrc = reinterpret_cast<const float4*>(W + (long)ks * 64);
            float4* wdst = reinterpret_cast<float4*>(&ws[0][0]);
#pragma unroll
            for (int i = 0; i < 4; ++i) wdst[t + 256 * i] = wsrc[t + 256 * i];
        }
        __syncthreads();
#pragma unroll 8
        for (int kk = 0; kk < 64; kk += 2){
            float2 a[3];
#pragma unroll
            for (int i = 0; i < 3; ++i)
                a[i] = *reinterpret_cast<const float2*>(&xs[tr + 16 * i][kk]);
            float4 b0 = *reinterpret_cast<const float4*>(&ws[kk][tc * 4]);
            float4 b1 = *reinterpret_cast<const float4*>(&ws[kk + 1][tc * 4]);
#pragma unroll
            for (int i = 0; i < 3; ++i){
                acc[i][0] = fmaf(a[i].x, b0.x, acc[i][0]);
                acc[i][1] = fmaf(a[i].x, b0.y, acc[i][1]);
                acc[i][2] = fmaf(a[i].x, b0.z, acc[i][2]);
                acc[i][3] = fmaf(a[i].x, b0.w, acc[i][3]);
                acc[i][0] = fmaf(a[i].y, b1.x, acc[i][0]);
                acc[i][1] = fmaf(a[i].y, b1.y, acc[i][1]);
                acc[i][2] = fmaf(a[i].y, b1.z, acc[i][2]);
                acc[i][3] = fmaf(a[i].y, b1.w, acc[i][3]);
            }
        }
    }

    // ---- epilogue 1: feat = leaky(BN(acc + b)) -> xs; stage Wg -> ws ----
    const float4 b4  = reinterpret_cast<const float4*>(b)[tc];
    const float4 g4  = reinterpret_cast<const float4*>(g)[tc];
    const float4 be4 = reinterpret_cast<const float4*>(beta)[tc];
    __syncthreads();    // all reads of xs/ws done
#pragma unroll
    for (int i = 0; i < 3; ++i){
        int r = tr + 16 * i;
        float4 h;
        h.x = (acc[i][0] + b4.x) * (g4.x * 0.99999500003749943f) + be4.x;
        h.y = (acc[i][1] + b4.y) * (g4.y * 0.99999500003749943f) + be4.y;
        h.z = (acc[i][2] + b4.z) * (g4.z * 0.99999500003749943f) + be4.z;
        h.w = (acc[i][3] + b4.w) * (g4.w * 0.99999500003749943f) + be4.w;
        h.x = (h.x >= 0.f) ? h.x : 0.01f * h.x;
        h.y = (h.y >= 0.f) ? h.y : 0.01f * h.y;
        h.z = (h.z >= 0.f) ? h.z : 0.01f * h.z;
        h.w = (h.w >= 0.f) ? h.w : 0.01f * h.w;
        *reinterpret_cast<float4*>(&xs[r][tc * 4]) = h;
    }
    {
        const float4* wsrc = reinterpret_cast<const float4*>(Wg);
        float4* wdst = reinterpret_cast<float4*>(&ws[0][0]);
#pragma unroll
        for (int i = 0; i < 4; ++i) wdst[t + 256 * i] = wsrc[t + 256 * i];
    }
    __syncthreads();

    // ---- gate GEMM: feat @ Wg (K = 64) ----
    float ac2[3][4];
#pragma unroll
    for (int i = 0; i < 3; ++i)
#pragma unroll
        for (int j = 0; j < 4; ++j) ac2[i][j] = 0.f;
#pragma unroll 8
    for (int kk = 0; kk < 64; kk += 2){
        float2 a[3];
#pragma unroll
        for (int i = 0; i < 3; ++i)
            a[i] = *reinterpret_cast<const float2*>(&xs[tr + 16 * i][kk]);
        float4 b0 = *reinterpret_cast<const float4*>(&ws[kk][tc * 4]);
        float4 b1 = *reinterpret_cast<const float4*>(&ws[kk + 1][tc * 4]);
#pragma unroll
        for (int i = 0; i < 3; ++i){
            ac2[i][0] = fmaf(a[i].x, b0.x, ac2[i][0]);
            ac2[i][1] = fmaf(a[i].x, b0.y, ac2[i][1]);
            ac2[i][2] = fmaf(a[i].x, b0.z, ac2[i][2]);
            ac2[i][3] = fmaf(a[i].x, b0.w, ac2[i][3]);
            ac2[i][0] = fmaf(a[i].y, b1.x, ac2[i][0]);
            ac2[i][1] = fmaf(a[i].y, b1.y, ac2[i][1]);
            ac2[i][2] = fmaf(a[i].y, b1.z, ac2[i][2]);
            ac2[i][3] = fmaf(a[i].y, b1.w, ac2[i][3]);
        }
    }

    // ---- epilogue 2: P = item * sigmoid(ac2 + bg) ----
    const float4 bg4 = reinterpret_cast<const float4*>(bg)[tc];
#pragma unroll
    for (int i = 0; i < 3; ++i){
        int r = tr + 16 * i;
        const float4 iv = *reinterpret_cast<const float4*>(
                item + (long)(row0 + r) * 64 + tc * 4);
        float4 o;
        o.x = iv.x / (1.f + __expf(-(ac2[i][0] + bg4.x)));
        o.y = iv.y / (1.f + __expf(-(ac2[i][1] + bg4.y)));
        o.z = iv.z / (1.f + __expf(-(ac2[i][2] + bg4.z)));
        o.w = iv.w / (1.f + __expf(-(ac2[i][3] + bg4.w)));
        *reinterpret_cast<float4*>(outP + (long)(row0 + r) * 64 + tc * 4) = o;
    }
}

// ---------------- copy ID elements ----------------
__global__ void k_copy(const float* __restrict__ s, float* __restrict__ d){
    int i = blockIdx.x * 256 + threadIdx.x;
    d[i] = s[i];
}

// ---------------- attention fusion; reads o1/o2, rewrites o1/o2/o3 in place ----------------
__global__ __launch_bounds__(256) void k_fuse(const float* __restrict__ img,
        const float* __restrict__ txt, const float* __restrict__ W1,
        const float* __restrict__ b1, const float* __restrict__ w2,
        float* __restrict__ out){
    __shared__ float si[4][64], st[4][64];
    const int t = threadIdx.x;
    const int w = t >> 6, c = t & 63;
    const long row = (long)blockIdx.x * 4 + w;
    float ie = img[row * 64 + c];
    float te = txt[row * 64 + c];
    si[w][c] = ie;  st[w][c] = te;
    __syncthreads();
    float ai = 0.f, at = 0.f;
#pragma unroll
    for (int k = 0; k < 64; ++k){
        float wv = W1[k * 64 + c];
        ai = fmaf(si[w][k], wv, ai);
        at = fmaf(st[w][k], wv, at);
    }
    float bb = b1[c];
    float hi = ai + bb; hi = (hi >= 0.f) ? hi : 0.01f * hi;
    float ht = at + bb; ht = (ht >= 0.f) ? ht : 0.01f * ht;
    float wc = w2[c];
    float pi = hi * wc, pt = ht * wc;
#pragma unroll
    for (int m = 1; m < 64; m <<= 1){
        pi += __shfl_xor(pi, m, 64);
        pt += __shfl_xor(pt, m, 64);
    }
    float mx = fmaxf(pi, pt);
    float ei = __expf(pi - mx), et = __expf(pt - mx);
    float inv = 1.f / (ei + et);
    float wi = ei * inv, wt = et * inv;
    float common = wi * ie + wt * te;
    const long NTD = (long)NTOT * DIM;
    long o = row * 64 + c;
    out[NTD + o]     = ie - common;
    out[2 * NTD + o] = te - common;
    out[3 * NTD + o] = common;
}

extern "C" void kernel_launch(void* const* d_in, const int* in_sizes, int n_in,
                              void* d_out, int out_size, void* d_ws, size_t ws_size,
                              hipStream_t stream){
    const float* user_emb  = (const float*)d_in[0];
    const float* item_emb  = (const float*)d_in[1];
    const float* image_emb = (const float*)d_in[2];
    const float* text_emb  = (const float*)d_in[3];
    const float* W_img = (const float*)d_in[4];
    const float* b_img = (const float*)d_in[5];
    const float* g_img = (const float*)d_in[6];
    const float* be_img= (const float*)d_in[7];
    const float* W_txt = (const float*)d_in[8];
    const float* b_txt = (const float*)d_in[9];
    const float* g_txt = (const float*)d_in[10];
    const float* be_txt= (const float*)d_in[11];
    const float* W_gi  = (const float*)d_in[12];
    const float* b_gi  = (const float*)d_in[13];
    const float* W_gt  = (const float*)d_in[14];
    const float* b_gt  = (const float*)d_in[15];
    const float* W_c1  = (const float*)d_in[16];
    const float* b_c1  = (const float*)d_in[17];
    const float* w_c2  = (const float*)d_in[18];
    const float* ui_vals = (const float*)d_in[19];
    const float* R_vals  = (const float*)d_in[20];
    const float* ii_iv   = (const float*)d_in[21];
    const float* ii_tv   = (const float*)d_in[22];
    const int* ui_rows = (const int*)d_in[23];
    const int* ui_cols = (const int*)d_in[24];
    const int* R_rows  = (const int*)d_in[25];
    const int* R_cols  = (const int*)d_in[26];
    const int* ii_ir   = (const int*)d_in[27];
    const int* ii_ic   = (const int*)d_in[28];
    const int* ii_tr   = (const int*)d_in[29];
    const int* ii_tc   = (const int*)d_in[30];

    const long ND = (long)NTOT * DIM;    // 5,120,000
    const long ID = (long)N_ITEM * DIM;  // 1,920,000
    const long UD = (long)N_USER * DIM;  // 3,200,000

    float* out = (float*)d_out;
    float* o0 = out;
    float* o1 = out + ND;
    float* o2 = out + 2 * ND;
    float* o3 = out + 3 * ND;

    // P/Q scratch live in o3 (free until k_fuse): 2*ID <= ND
    float* P = o3;
    float* Q = o3 + ID;

    // binned staging (19.2 MB) lives in o0 — dead until k_content.
    int2* binned = (int2*)o0;

    // ---- workspace (~20 MB): combined CSR + bucket tables ----
    int2* csr   = (int2*)d_ws;                  // NNZ_ALL (19.2 MB)
    int*  off   = (int*)(csr + NNZ_ALL);        // NROWS_ALL + 1 (+pad)
    int*  bcnt  = off + NROWS_ALL + 4;          // NBUCK
    int*  bcur  = bcnt + NBUCK;                 // NBUCK (adjacent: one memset)
    int*  bbase = bcur + NBUCK;                 // NBUCK + 1

    // ---- build combined CSR: bucket-hist -> scan -> bin -> per-bucket scatter
    hipMemsetAsync(bcnt, 0, 2 * NBUCK * sizeof(int), stream);   // bcnt + bcur
    k_bhist<<<512, 256, 0, stream>>>(ui_rows, R_rows, ii_ir, ii_tr, bcnt);
    k_bscan<<<1, 512, 0, stream>>>(bcnt, bbase, off);
    k_bin<<<NBLK_A2, 256, 0, stream>>>(
        ui_rows, ui_cols, ui_vals,  R_rows, R_cols, R_vals,
        ii_ir, ii_ic, ii_iv,        ii_tr, ii_tc, ii_tv,
        bbase, bcur, binned);
    k_scatter<<<NBUCK, 256, 0, stream>>>(bbase, binned, off, csr);

    const int* offUI = off;
    const int* offR  = off + BASE_R;
    const int* offI2 = off + BASE_II;
    const int* offT2 = off + BASE_IT;

    // ---- content branch ----
    k_cat0<<<ND / 256, 256, 0, stream>>>(item_emb, user_emb, o1);
    k_pull<<<NTOT / 16, 256, 0, stream>>>(offUI, csr, o1, o2, NTOT);
    k_pull<<<NTOT / 16, 256, 0, stream>>>(offUI, csr, o2, o3, NTOT);
    k_content<<<ND / 256, 256, 0, stream>>>(o1, o2, o3, o0);
    // o0 (binned) overwritten only here; o3 (P/Q scratch) free again from here

    // ---- image branch -> o1 ----
    k_projgate<IMG_F><<<N_ITEM / 48, 256, 0, stream>>>(
        image_emb, W_img, b_img, g_img, be_img, W_gi, b_gi, item_emb, P);
    k_pull<<<N_ITEM / 16, 256, 0, stream>>>(offI2, csr, P, Q, N_ITEM);
    k_pull<<<N_ITEM / 16, 256, 0, stream>>>(offI2, csr, Q, P, N_ITEM);
    k_pull<<<N_USER / 16, 256, 0, stream>>>(offR, csr, P, o1, N_USER);
    k_copy<<<ID / 256, 256, 0, stream>>>(P, o1 + UD);

    // ---- text branch -> o2 ----
    k_projgate<TXT_F><<<N_ITEM / 48, 256, 0, stream>>>(
        text_emb, W_txt, b_txt, g_txt, be_txt, W_gt, b_gt, item_emb, P);
    k_pull<<<N_ITEM / 16, 256, 0, stream>>>(offT2, csr, P, Q, N_ITEM);
    k_pull<<<N_ITEM / 16, 256, 0, stream>>>(offT2, csr, Q, P, N_ITEM);
    k_pull<<<N_USER / 16, 256, 0, stream>>>(offR, csr, P, o2, N_USER);
    k_copy<<<ID / 256, 256, 0, stream>>>(P, o2 + UD);

    // ---- fusion epilogue (in-place on o1/o2, writes o3) ----
    k_fuse<<<NTOT / 4, 256, 0, stream>>>(o1, o2, W_c1, b_c1, w_c2, out);
}

// Round 3
// 592.517 us; speedup vs baseline: 1.7590x; 1.0746x over previous
//
#include <hip/hip_runtime.h>

#define N_USER 50000
#define N_ITEM 30000
#define DIM    64
#define NTOT   80000
#define NNZ_UI 1000000
#define NNZ_R  800000
#define NNZ_II 300000
#define IMG_F  512
#define TXT_F  384

#define NROWS_ALL 190000            // NTOT + N_USER + N_ITEM + N_ITEM
#define NNZ_ALL   2400000           // NNZ_UI + NNZ_R + 2*NNZ_II
#define BASE_R    NTOT              // 80000
#define BASE_II   (NTOT + N_USER)   // 130000
#define BASE_IT   (NTOT + N_USER + N_ITEM) // 160000

// row-bucketed CSR build: 512 rows per bucket
#define RB_BITS   9
#define RB_ROWS   512
#define NBUCK     ((NROWS_ALL + RB_ROWS - 1) / RB_ROWS)   // 372
#define NBLK_A2   400
#define EDG_A2    6000              // 400 * 6000 == NNZ_ALL exactly

// ---------------- edge decode helpers (fused 4-list view) ----------------
__device__ __forceinline__ int edge_row(int i,
        const int* __restrict__ r0, const int* __restrict__ r1,
        const int* __restrict__ r2, const int* __restrict__ r3){
    if (i < NNZ_UI)                       return r0[i];
    if (i < NNZ_UI + NNZ_R)               return BASE_R  + r1[i - NNZ_UI];
    if (i < NNZ_UI + NNZ_R + NNZ_II)      return BASE_II + r2[i - NNZ_UI - NNZ_R];
    return BASE_IT + r3[i - NNZ_UI - NNZ_R - NNZ_II];
}

__device__ __forceinline__ void edge_all(int i,
        const int* __restrict__ r0, const int* __restrict__ c0, const float* __restrict__ v0,
        const int* __restrict__ r1, const int* __restrict__ c1, const float* __restrict__ v1,
        const int* __restrict__ r2, const int* __restrict__ c2, const float* __restrict__ v2,
        const int* __restrict__ r3, const int* __restrict__ c3, const float* __restrict__ v3,
        int& gr, int& col, float& val){
    if (i < NNZ_UI){
        gr = r0[i]; col = c0[i]; val = v0[i];
    } else if (i < NNZ_UI + NNZ_R){
        int j = i - NNZ_UI;               gr = BASE_R  + r1[j]; col = c1[j]; val = v1[j];
    } else if (i < NNZ_UI + NNZ_R + NNZ_II){
        int j = i - NNZ_UI - NNZ_R;       gr = BASE_II + r2[j]; col = c2[j]; val = v2[j];
    } else {
        int j = i - NNZ_UI - NNZ_R - NNZ_II; gr = BASE_IT + r3[j]; col = c3[j]; val = v3[j];
    }
}

// ---------------- build 1: bucket histogram (LDS-aggregated) ----------------
__global__ __launch_bounds__(256) void k_bhist(const int* __restrict__ r0,
        const int* __restrict__ r1, const int* __restrict__ r2,
        const int* __restrict__ r3, int* __restrict__ bcnt){
    __shared__ int h[NBUCK];
    for (int i = threadIdx.x; i < NBUCK; i += 256) h[i] = 0;
    __syncthreads();
    const int stride = gridDim.x * 256;
    for (int i = blockIdx.x * 256 + threadIdx.x; i < NNZ_ALL; i += stride){
        int gr = edge_row(i, r0, r1, r2, r3);
        atomicAdd(&h[gr >> RB_BITS], 1);
    }
    __syncthreads();
    for (int i = threadIdx.x; i < NBUCK; i += 256){
        int c = h[i];
        if (c) atomicAdd(&bcnt[i], c);
    }
}

// ---------------- build 2: scan bucket counts (single block) ----------------
__global__ __launch_bounds__(512) void k_bscan(const int* __restrict__ bcnt,
        int* __restrict__ bbase, int* __restrict__ off){
    __shared__ int sh[512];
    const int t = threadIdx.x;
    int v = (t < NBUCK) ? bcnt[t] : 0;
    sh[t] = v;
    __syncthreads();
    for (int d = 1; d < 512; d <<= 1){
        int u = (t >= d) ? sh[t - d] : 0;
        __syncthreads();
        sh[t] += u;
        __syncthreads();
    }
    if (t < NBUCK) bbase[t] = sh[t] - v;          // exclusive prefix
    if (t == NBUCK - 1){
        bbase[NBUCK] = sh[t];                      // grand total (== NNZ_ALL)
        off[NROWS_ALL] = sh[t];
    }
}

// ---------------- build 3: bin edges into bucket-major staging ----------------
// rec.x = (col << 9) | (gr & 511), rec.y = bits(val). col < 2^17, so fits.
__global__ __launch_bounds__(256) void k_bin(
        const int* __restrict__ r0, const int* __restrict__ c0, const float* __restrict__ v0,
        const int* __restrict__ r1, const int* __restrict__ c1, const float* __restrict__ v1,
        const int* __restrict__ r2, const int* __restrict__ c2, const float* __restrict__ v2,
        const int* __restrict__ r3, const int* __restrict__ c3, const float* __restrict__ v3,
        const int* __restrict__ bbase, int* __restrict__ bcur,
        int2* __restrict__ binned){
    __shared__ int lofs[NBUCK];
    __shared__ int lcur[NBUCK];
    const int t = threadIdx.x;
    for (int i = t; i < NBUCK; i += 256){ lofs[i] = 0; lcur[i] = 0; }
    __syncthreads();
    const int s0 = blockIdx.x * EDG_A2, s1 = s0 + EDG_A2;
    // pass 1: local bucket histogram
    for (int i = s0 + t; i < s1; i += 256){
        int gr = edge_row(i, r0, r1, r2, r3);
        atomicAdd(&lofs[gr >> RB_BITS], 1);
    }
    __syncthreads();
    // reserve per-bucket chunks (one global atomic per (block,bucket))
    for (int i = t; i < NBUCK; i += 256){
        int c = lofs[i];
        lofs[i] = c ? (bbase[i] + atomicAdd(&bcur[i], c)) : 0;
    }
    __syncthreads();
    // pass 2: write packed records into this block's chunks
    for (int i = s0 + t; i < s1; i += 256){
        int gr, col; float val;
        edge_all(i, r0, c0, v0, r1, c1, v1, r2, c2, v2, r3, c3, v3, gr, col, val);
        int b = gr >> RB_BITS;
        int slot = atomicAdd(&lcur[b], 1);
        binned[lofs[b] + slot] = make_int2((col << RB_BITS) | (gr & (RB_ROWS - 1)),
                                           __float_as_int(val));
    }
}

// ---------------- build 4: per-bucket hist+scan+scatter (one block = one bucket)
__global__ __launch_bounds__(256) void k_scatter(const int* __restrict__ bbase,
        const int2* __restrict__ binned, int* __restrict__ off,
        int2* __restrict__ csr){
    __shared__ int h[RB_ROWS];
    const int t = threadIdx.x;
    const int b = blockIdx.x;
    const int base = bbase[b];
    const int nb = bbase[b + 1] - base;
    h[t] = 0; h[t + 256] = 0;
    __syncthreads();
    // local row histogram
    for (int i = t; i < nb; i += 256)
        atomicAdd(&h[binned[base + i].x & (RB_ROWS - 1)], 1);
    __syncthreads();
    // exclusive scan of 512 counters by wave 0 (8 elems/lane + shfl scan)
    if (t < 64){
        int v[8], s = 0;
#pragma unroll
        for (int k = 0; k < 8; ++k){ v[k] = h[t * 8 + k]; s += v[k]; }
        int incl = s;
#pragma unroll
        for (int d = 1; d < 64; d <<= 1){
            int u = __shfl_up(incl, d, 64);
            if (t >= d) incl += u;
        }
        int run = incl - s;
#pragma unroll
        for (int k = 0; k < 8; ++k){ int tmp = v[k]; h[t * 8 + k] = run; run += tmp; }
    }
    __syncthreads();
    // emit row offsets
    const int row0 = b << RB_BITS;
    for (int i = t; i < RB_ROWS; i += 256){
        int r = row0 + i;
        if (r < NROWS_ALL) off[r] = base + h[i];
    }
    __syncthreads();
    // scatter into private CSR window; h[] doubles as row cursors
    for (int i = t; i < nb; i += 256){
        int2 rec = binned[base + i];
        int lr = rec.x & (RB_ROWS - 1);
        int slot = atomicAdd(&h[lr], 1);
        csr[base + slot] = make_int2(rec.x >> RB_BITS, rec.y);
    }
}

// ---------------- cat0 = [item_emb; user_emb] ----------------
__global__ void k_cat0(const float* __restrict__ item, const float* __restrict__ user,
                       float* __restrict__ o1){
    int i = blockIdx.x * 256 + threadIdx.x;
    const int ITEMS = N_ITEM * DIM;
    o1[i] = (i < ITEMS) ? item[i] : user[i - ITEMS];
}

// ---------------- pull-SpMM: y[r] = sum val*x[col], one row per 16 lanes ----------------
__global__ void k_pull(const int* __restrict__ off, const int2* __restrict__ csr,
                       const float* __restrict__ x, float* __restrict__ y, int nrows){
    int t = blockIdx.x * 256 + threadIdx.x;
    int r = t >> 4;
    if (r >= nrows) return;
    int l = (t & 15) << 2;
    int s = off[r], e = off[r + 1];
    float4 a0 = {0.f, 0.f, 0.f, 0.f};
    float4 a1 = {0.f, 0.f, 0.f, 0.f};
    int j = s;
    for (; j + 2 <= e; j += 2){
        int2 e0 = csr[j];
        int2 e1 = csr[j + 1];
        float v0 = __int_as_float(e0.y);
        float v1 = __int_as_float(e1.y);
        const float4 x0 = *reinterpret_cast<const float4*>(x + ((long)e0.x << 6) + l);
        const float4 x1 = *reinterpret_cast<const float4*>(x + ((long)e1.x << 6) + l);
        a0.x = fmaf(v0, x0.x, a0.x);
        a0.y = fmaf(v0, x0.y, a0.y);
        a0.z = fmaf(v0, x0.z, a0.z);
        a0.w = fmaf(v0, x0.w, a0.w);
        a1.x = fmaf(v1, x1.x, a1.x);
        a1.y = fmaf(v1, x1.y, a1.y);
        a1.z = fmaf(v1, x1.z, a1.z);
        a1.w = fmaf(v1, x1.w, a1.w);
    }
    if (j < e){
        int2 e0 = csr[j];
        float v0 = __int_as_float(e0.y);
        const float4 x0 = *reinterpret_cast<const float4*>(x + ((long)e0.x << 6) + l);
        a0.x = fmaf(v0, x0.x, a0.x);
        a0.y = fmaf(v0, x0.y, a0.y);
        a0.z = fmaf(v0, x0.z, a0.z);
        a0.w = fmaf(v0, x0.w, a0.w);
    }
    a0.x += a1.x; a0.y += a1.y; a0.z += a1.z; a0.w += a1.w;
    *reinterpret_cast<float4*>(y + ((long)r << 6) + l) = a0;
}

// ---------------- pull + content mean fused: o0 = (a + x_row + pull(x))/3 ----
// Replaces the 2nd UI pull + k_content; cat2 is never materialized.
__global__ void k_pull_mean(const int* __restrict__ off, const int2* __restrict__ csr,
                            const float* __restrict__ x, const float* __restrict__ a,
                            float* __restrict__ o0, int nrows){
    int t = blockIdx.x * 256 + threadIdx.x;
    int r = t >> 4;
    if (r >= nrows) return;
    int l = (t & 15) << 2;
    int s = off[r], e = off[r + 1];
    float4 a0 = {0.f, 0.f, 0.f, 0.f};
    float4 a1 = {0.f, 0.f, 0.f, 0.f};
    int j = s;
    for (; j + 2 <= e; j += 2){
        int2 e0 = csr[j];
        int2 e1 = csr[j + 1];
        float v0 = __int_as_float(e0.y);
        float v1 = __int_as_float(e1.y);
        const float4 x0 = *reinterpret_cast<const float4*>(x + ((long)e0.x << 6) + l);
        const float4 x1 = *reinterpret_cast<const float4*>(x + ((long)e1.x << 6) + l);
        a0.x = fmaf(v0, x0.x, a0.x);
        a0.y = fmaf(v0, x0.y, a0.y);
        a0.z = fmaf(v0, x0.z, a0.z);
        a0.w = fmaf(v0, x0.w, a0.w);
        a1.x = fmaf(v1, x1.x, a1.x);
        a1.y = fmaf(v1, x1.y, a1.y);
        a1.z = fmaf(v1, x1.z, a1.z);
        a1.w = fmaf(v1, x1.w, a1.w);
    }
    if (j < e){
        int2 e0 = csr[j];
        float v0 = __int_as_float(e0.y);
        const float4 x0 = *reinterpret_cast<const float4*>(x + ((long)e0.x << 6) + l);
        a0.x = fmaf(v0, x0.x, a0.x);
        a0.y = fmaf(v0, x0.y, a0.y);
        a0.z = fmaf(v0, x0.z, a0.z);
        a0.w = fmaf(v0, x0.w, a0.w);
    }
    const float4 av = *reinterpret_cast<const float4*>(a + ((long)r << 6) + l);
    const float4 xv = *reinterpret_cast<const float4*>(x + ((long)r << 6) + l);
    float4 o;
    o.x = (av.x + xv.x + a0.x + a1.x) * (1.0f / 3.0f);
    o.y = (av.y + xv.y + a0.y + a1.y) * (1.0f / 3.0f);
    o.z = (av.z + xv.z + a0.z + a1.z) * (1.0f / 3.0f);
    o.w = (av.w + xv.w + a0.w + a1.w) * (1.0f / 3.0f);
    *reinterpret_cast<float4*>(o0 + ((long)r << 6) + l) = o;
}

// ---------------- fused projection + gate ----------------
// P = item_emb * sigmoid( leaky(BN(X@W + b)) @ Wg + bg )
template<int K>
__global__ __launch_bounds__(256) void k_projgate(
        const float* __restrict__ X,
        const float* __restrict__ W,  const float* __restrict__ b,
        const float* __restrict__ g,  const float* __restrict__ beta,
        const float* __restrict__ Wg, const float* __restrict__ bg,
        const float* __restrict__ item, float* __restrict__ outP){
    __shared__ float xs[48][68];    // +4 pad: a-frag reads conflict-free, f4-aligned
    __shared__ float ws[64][64];
    const int t  = threadIdx.x;
    const int tr = t >> 4;          // 0..15
    const int tc = t & 15;          // 0..15
    const int row0 = blockIdx.x * 48;

    float acc[3][4];
#pragma unroll
    for (int i = 0; i < 3; ++i)
#pragma unroll
        for (int j = 0; j < 4; ++j) acc[i][j] = 0.f;

    for (int ks = 0; ks < K; ks += 64){
        __syncthreads();
        // stage X tile [48][64]
#pragma unroll
        for (int i = 0; i < 3; ++i){
            int r = tr + 16 * i;
            *reinterpret_cast<float4*>(&xs[r][tc * 4]) =
                *reinterpret_cast<const float4*>(X + (long)(row0 + r) * K + ks + tc * 4);
        }
        // stage W tile [64][64] (contiguous 16 KB)
        {
            const float4* wsrc = reinterpret_cast<const float4*>(W + (long)ks * 64);
            float4* wdst = reinterpret_cast<float4*>(&ws[0][0]);
#pragma unroll
            for (int i = 0; i < 4; ++i) wdst[t + 256 * i] = wsrc[t + 256 * i];
        }
        __syncthreads();
#pragma unroll 8
        for (int kk = 0; kk < 64; kk += 2){
            float2 a[3];
#pragma unroll
            for (int i = 0; i < 3; ++i)
                a[i] = *reinterpret_cast<const float2*>(&xs[tr + 16 * i][kk]);
            float4 b0 = *reinterpret_cast<const float4*>(&ws[kk][tc * 4]);
            float4 b1 = *reinterpret_cast<const float4*>(&ws[kk + 1][tc * 4]);
#pragma unroll
            for (int i = 0; i < 3; ++i){
                acc[i][0] = fmaf(a[i].x, b0.x, acc[i][0]);
                acc[i][1] = fmaf(a[i].x, b0.y, acc[i][1]);
                acc[i][2] = fmaf(a[i].x, b0.z, acc[i][2]);
                acc[i][3] = fmaf(a[i].x, b0.w, acc[i][3]);
                acc[i][0] = fmaf(a[i].y, b1.x, acc[i][0]);
                acc[i][1] = fmaf(a[i].y, b1.y, acc[i][1]);
                acc[i][2] = fmaf(a[i].y, b1.z, acc[i][2]);
                acc[i][3] = fmaf(a[i].y, b1.w, acc[i][3]);
            }
        }
    }

    // ---- epilogue 1: feat = leaky(BN(acc + b)) -> xs; stage Wg -> ws ----
    const float4 b4  = reinterpret_cast<const float4*>(b)[tc];
    const float4 g4  = reinterpret_cast<const float4*>(g)[tc];
    const float4 be4 = reinterpret_cast<const float4*>(beta)[tc];
    __syncthreads();    // all reads of xs/ws done
#pragma unroll
    for (int i = 0; i < 3; ++i){
        int r = tr + 16 * i;
        float4 h;
        h.x = (acc[i][0] + b4.x) * (g4.x * 0.99999500003749943f) + be4.x;
        h.y = (acc[i][1] + b4.y) * (g4.y * 0.99999500003749943f) + be4.y;
        h.z = (acc[i][2] + b4.z) * (g4.z * 0.99999500003749943f) + be4.z;
        h.w = (acc[i][3] + b4.w) * (g4.w * 0.99999500003749943f) + be4.w;
        h.x = (h.x >= 0.f) ? h.x : 0.01f * h.x;
        h.y = (h.y >= 0.f) ? h.y : 0.01f * h.y;
        h.z = (h.z >= 0.f) ? h.z : 0.01f * h.z;
        h.w = (h.w >= 0.f) ? h.w : 0.01f * h.w;
        *reinterpret_cast<float4*>(&xs[r][tc * 4]) = h;
    }
    {
        const float4* wsrc = reinterpret_cast<const float4*>(Wg);
        float4* wdst = reinterpret_cast<float4*>(&ws[0][0]);
#pragma unroll
        for (int i = 0; i < 4; ++i) wdst[t + 256 * i] = wsrc[t + 256 * i];
    }
    __syncthreads();

    // ---- gate GEMM: feat @ Wg (K = 64) ----
    float ac2[3][4];
#pragma unroll
    for (int i = 0; i < 3; ++i)
#pragma unroll
        for (int j = 0; j < 4; ++j) ac2[i][j] = 0.f;
#pragma unroll 8
    for (int kk = 0; kk < 64; kk += 2){
        float2 a[3];
#pragma unroll
        for (int i = 0; i < 3; ++i)
            a[i] = *reinterpret_cast<const float2*>(&xs[tr + 16 * i][kk]);
        float4 b0 = *reinterpret_cast<const float4*>(&ws[kk][tc * 4]);
        float4 b1 = *reinterpret_cast<const float4*>(&ws[kk + 1][tc * 4]);
#pragma unroll
        for (int i = 0; i < 3; ++i){
            ac2[i][0] = fmaf(a[i].x, b0.x, ac2[i][0]);
            ac2[i][1] = fmaf(a[i].x, b0.y, ac2[i][1]);
            ac2[i][2] = fmaf(a[i].x, b0.z, ac2[i][2]);
            ac2[i][3] = fmaf(a[i].x, b0.w, ac2[i][3]);
            ac2[i][0] = fmaf(a[i].y, b1.x, ac2[i][0]);
            ac2[i][1] = fmaf(a[i].y, b1.y, ac2[i][1]);
            ac2[i][2] = fmaf(a[i].y, b1.z, ac2[i][2]);
            ac2[i][3] = fmaf(a[i].y, b1.w, ac2[i][3]);
        }
    }

    // ---- epilogue 2: P = item * sigmoid(ac2 + bg) ----
    const float4 bg4 = reinterpret_cast<const float4*>(bg)[tc];
#pragma unroll
    for (int i = 0; i < 3; ++i){
        int r = tr + 16 * i;
        const float4 iv = *reinterpret_cast<const float4*>(
                item + (long)(row0 + r) * 64 + tc * 4);
        float4 o;
        o.x = iv.x / (1.f + __expf(-(ac2[i][0] + bg4.x)));
        o.y = iv.y / (1.f + __expf(-(ac2[i][1] + bg4.y)));
        o.z = iv.z / (1.f + __expf(-(ac2[i][2] + bg4.z)));
        o.w = iv.w / (1.f + __expf(-(ac2[i][3] + bg4.w)));
        *reinterpret_cast<float4*>(outP + (long)(row0 + r) * 64 + tc * 4) = o;
    }
}

// ---------------- attention fusion, register-tiled ----------------
// 64 rows x 64 cols per 256-thread block; W1 staged once, shared by both
// modality GEMMs. Thread (tr,tc): rows {tr+16i}, cols tc*4..+3.
__global__ __launch_bounds__(256) void k_fuse(const float* __restrict__ img,
        const float* __restrict__ txt, const float* __restrict__ W1,
        const float* __restrict__ b1, const float* __restrict__ w2,
        float* __restrict__ out){
    __shared__ float si[64][68];
    __shared__ float st[64][68];
    __shared__ float w1s[64][64];
    const int t  = threadIdx.x;
    const int tr = t >> 4;          // 0..15
    const int tc = t & 15;          // 0..15
    const long row0 = (long)blockIdx.x * 64;

    // stage img/txt tiles + W1
#pragma unroll
    for (int i = 0; i < 4; ++i){
        int r = tr + 16 * i;
        *reinterpret_cast<float4*>(&si[r][tc * 4]) =
            *reinterpret_cast<const float4*>(img + (row0 + r) * 64 + tc * 4);
        *reinterpret_cast<float4*>(&st[r][tc * 4]) =
            *reinterpret_cast<const float4*>(txt + (row0 + r) * 64 + tc * 4);
    }
    {
        const float4* wsrc = reinterpret_cast<const float4*>(W1);
        float4* wdst = reinterpret_cast<float4*>(&w1s[0][0]);
#pragma unroll
        for (int i = 0; i < 4; ++i) wdst[t + 256 * i] = wsrc[t + 256 * i];
    }
    __syncthreads();

    float ai[4][4], at[4][4];
#pragma unroll
    for (int i = 0; i < 4; ++i)
#pragma unroll
        for (int j = 0; j < 4; ++j){ ai[i][j] = 0.f; at[i][j] = 0.f; }

#pragma unroll 8
    for (int kk = 0; kk < 64; kk += 2){
        float4 b0 = *reinterpret_cast<const float4*>(&w1s[kk][tc * 4]);
        float4 b1v = *reinterpret_cast<const float4*>(&w1s[kk + 1][tc * 4]);
#pragma unroll
        for (int i = 0; i < 4; ++i){
            float2 a = *reinterpret_cast<const float2*>(&si[tr + 16 * i][kk]);
            float2 c = *reinterpret_cast<const float2*>(&st[tr + 16 * i][kk]);
            ai[i][0] = fmaf(a.x, b0.x, ai[i][0]);
            ai[i][1] = fmaf(a.x, b0.y, ai[i][1]);
            ai[i][2] = fmaf(a.x, b0.z, ai[i][2]);
            ai[i][3] = fmaf(a.x, b0.w, ai[i][3]);
            ai[i][0] = fmaf(a.y, b1v.x, ai[i][0]);
            ai[i][1] = fmaf(a.y, b1v.y, ai[i][1]);
            ai[i][2] = fmaf(a.y, b1v.z, ai[i][2]);
            ai[i][3] = fmaf(a.y, b1v.w, ai[i][3]);
            at[i][0] = fmaf(c.x, b0.x, at[i][0]);
            at[i][1] = fmaf(c.x, b0.y, at[i][1]);
            at[i][2] = fmaf(c.x, b0.z, at[i][2]);
            at[i][3] = fmaf(c.x, b0.w, at[i][3]);
            at[i][0] = fmaf(c.y, b1v.x, at[i][0]);
            at[i][1] = fmaf(c.y, b1v.y, at[i][1]);
            at[i][2] = fmaf(c.y, b1v.z, at[i][2]);
            at[i][3] = fmaf(c.y, b1v.w, at[i][3]);
        }
    }

    // leaky + dot with w2 over this thread's 4 cols
    const float4 b14 = reinterpret_cast<const float4*>(b1)[tc];
    const float4 w24 = reinterpret_cast<const float4*>(w2)[tc];
    float pi[4], pt[4];
#pragma unroll
    for (int i = 0; i < 4; ++i){
        float hi0 = ai[i][0] + b14.x; hi0 = (hi0 >= 0.f) ? hi0 : 0.01f * hi0;
        float hi1 = ai[i][1] + b14.y; hi1 = (hi1 >= 0.f) ? hi1 : 0.01f * hi1;
        float hi2 = ai[i][2] + b14.z; hi2 = (hi2 >= 0.f) ? hi2 : 0.01f * hi2;
        float hi3 = ai[i][3] + b14.w; hi3 = (hi3 >= 0.f) ? hi3 : 0.01f * hi3;
        float ht0 = at[i][0] + b14.x; ht0 = (ht0 >= 0.f) ? ht0 : 0.01f * ht0;
        float ht1 = at[i][1] + b14.y; ht1 = (ht1 >= 0.f) ? ht1 : 0.01f * ht1;
        float ht2 = at[i][2] + b14.z; ht2 = (ht2 >= 0.f) ? ht2 : 0.01f * ht2;
        float ht3 = at[i][3] + b14.w; ht3 = (ht3 >= 0.f) ? ht3 : 0.01f * ht3;
        pi[i] = fmaf(hi0, w24.x, fmaf(hi1, w24.y, fmaf(hi2, w24.z, hi3 * w24.w)));
        pt[i] = fmaf(ht0, w24.x, fmaf(ht1, w24.y, fmaf(ht2, w24.z, ht3 * w24.w)));
    }
    // reduce across the 16 lanes of the row group (xor masks < 16 stay in-group)
#pragma unroll
    for (int m = 1; m < 16; m <<= 1){
#pragma unroll
        for (int i = 0; i < 4; ++i){
            pi[i] += __shfl_xor(pi[i], m, 64);
            pt[i] += __shfl_xor(pt[i], m, 64);
        }
    }

    const long NTD = (long)NTOT * DIM;
#pragma unroll
    for (int i = 0; i < 4; ++i){
        int r = tr + 16 * i;
        float mx = fmaxf(pi[i], pt[i]);
        float ei = __expf(pi[i] - mx), et = __expf(pt[i] - mx);
        float inv = 1.f / (ei + et);
        float wi = ei * inv, wt = et * inv;
        const float4 ie = *reinterpret_cast<const float4*>(&si[r][tc * 4]);
        const float4 te = *reinterpret_cast<const float4*>(&st[r][tc * 4]);
        float4 cm, oi, ot;
        cm.x = wi * ie.x + wt * te.x;
        cm.y = wi * ie.y + wt * te.y;
        cm.z = wi * ie.z + wt * te.z;
        cm.w = wi * ie.w + wt * te.w;
        oi.x = ie.x - cm.x; oi.y = ie.y - cm.y; oi.z = ie.z - cm.z; oi.w = ie.w - cm.w;
        ot.x = te.x - cm.x; ot.y = te.y - cm.y; ot.z = te.z - cm.z; ot.w = te.w - cm.w;
        long o = (row0 + r) * 64 + tc * 4;
        *reinterpret_cast<float4*>(out + NTD + o)     = oi;
        *reinterpret_cast<float4*>(out + 2 * NTD + o) = ot;
        *reinterpret_cast<float4*>(out + 3 * NTD + o) = cm;
    }
}

extern "C" void kernel_launch(void* const* d_in, const int* in_sizes, int n_in,
                              void* d_out, int out_size, void* d_ws, size_t ws_size,
                              hipStream_t stream){
    const float* user_emb  = (const float*)d_in[0];
    const float* item_emb  = (const float*)d_in[1];
    const float* image_emb = (const float*)d_in[2];
    const float* text_emb  = (const float*)d_in[3];
    const float* W_img = (const float*)d_in[4];
    const float* b_img = (const float*)d_in[5];
    const float* g_img = (const float*)d_in[6];
    const float* be_img= (const float*)d_in[7];
    const float* W_txt = (const float*)d_in[8];
    const float* b_txt = (const float*)d_in[9];
    const float* g_txt = (const float*)d_in[10];
    const float* be_txt= (const float*)d_in[11];
    const float* W_gi  = (const float*)d_in[12];
    const float* b_gi  = (const float*)d_in[13];
    const float* W_gt  = (const float*)d_in[14];
    const float* b_gt  = (const float*)d_in[15];
    const float* W_c1  = (const float*)d_in[16];
    const float* b_c1  = (const float*)d_in[17];
    const float* w_c2  = (const float*)d_in[18];
    const float* ui_vals = (const float*)d_in[19];
    const float* R_vals  = (const float*)d_in[20];
    const float* ii_iv   = (const float*)d_in[21];
    const float* ii_tv   = (const float*)d_in[22];
    const int* ui_rows = (const int*)d_in[23];
    const int* ui_cols = (const int*)d_in[24];
    const int* R_rows  = (const int*)d_in[25];
    const int* R_cols  = (const int*)d_in[26];
    const int* ii_ir   = (const int*)d_in[27];
    const int* ii_ic   = (const int*)d_in[28];
    const int* ii_tr   = (const int*)d_in[29];
    const int* ii_tc   = (const int*)d_in[30];

    const long ND = (long)NTOT * DIM;    // 5,120,000
    const long ID = (long)N_ITEM * DIM;  // 1,920,000
    const long UD = (long)N_USER * DIM;  // 3,200,000

    float* out = (float*)d_out;
    float* o0 = out;
    float* o1 = out + ND;
    float* o2 = out + 2 * ND;
    float* o3 = out + 3 * ND;

    // P/Q scratch live in o3 (free until k_fuse): 2*ID <= ND
    float* P = o3;
    float* Q = o3 + ID;

    // binned staging (19.2 MB) lives in o0 — dead until k_pull_mean.
    int2* binned = (int2*)o0;

    // ---- workspace (~20 MB): combined CSR + bucket tables ----
    int2* csr   = (int2*)d_ws;                  // NNZ_ALL (19.2 MB)
    int*  off   = (int*)(csr + NNZ_ALL);        // NROWS_ALL + 1 (+pad)
    int*  bcnt  = off + NROWS_ALL + 4;          // NBUCK
    int*  bcur  = bcnt + NBUCK;                 // NBUCK (adjacent: one memset)
    int*  bbase = bcur + NBUCK;                 // NBUCK + 1

    // ---- build combined CSR: bucket-hist -> scan -> bin -> per-bucket scatter
    hipMemsetAsync(bcnt, 0, 2 * NBUCK * sizeof(int), stream);   // bcnt + bcur
    k_bhist<<<512, 256, 0, stream>>>(ui_rows, R_rows, ii_ir, ii_tr, bcnt);
    k_bscan<<<1, 512, 0, stream>>>(bcnt, bbase, off);
    k_bin<<<NBLK_A2, 256, 0, stream>>>(
        ui_rows, ui_cols, ui_vals,  R_rows, R_cols, R_vals,
        ii_ir, ii_ic, ii_iv,        ii_tr, ii_tc, ii_tv,
        bbase, bcur, binned);
    k_scatter<<<NBUCK, 256, 0, stream>>>(bbase, binned, off, csr);

    const int* offUI = off;
    const int* offR  = off + BASE_R;
    const int* offI2 = off + BASE_II;
    const int* offT2 = off + BASE_IT;

    // ---- content branch: cat2 never materialized ----
    k_cat0<<<ND / 256, 256, 0, stream>>>(item_emb, user_emb, o1);
    k_pull<<<NTOT / 16, 256, 0, stream>>>(offUI, csr, o1, o2, NTOT);
    k_pull_mean<<<NTOT / 16, 256, 0, stream>>>(offUI, csr, o2, o1, o0, NTOT);
    // o0 (binned) overwritten here; o3 (P/Q scratch) free throughout

    // ---- image branch -> o1 (item part written in place, no copy) ----
    k_projgate<IMG_F><<<N_ITEM / 48, 256, 0, stream>>>(
        image_emb, W_img, b_img, g_img, be_img, W_gi, b_gi, item_emb, P);
    k_pull<<<N_ITEM / 16, 256, 0, stream>>>(offI2, csr, P, Q, N_ITEM);
    k_pull<<<N_ITEM / 16, 256, 0, stream>>>(offI2, csr, Q, o1 + UD, N_ITEM);
    k_pull<<<N_USER / 16, 256, 0, stream>>>(offR, csr, o1 + UD, o1, N_USER);

    // ---- text branch -> o2 ----
    k_projgate<TXT_F><<<N_ITEM / 48, 256, 0, stream>>>(
        text_emb, W_txt, b_txt, g_txt, be_txt, W_gt, b_gt, item_emb, P);
    k_pull<<<N_ITEM / 16, 256, 0, stream>>>(offT2, csr, P, Q, N_ITEM);
    k_pull<<<N_ITEM / 16, 256, 0, stream>>>(offT2, csr, Q, o2 + UD, N_ITEM);
    k_pull<<<N_USER / 16, 256, 0, stream>>>(offR, csr, o2 + UD, o2, N_USER);

    // ---- fusion epilogue (reads o1/o2, writes o1/o2/o3) ----
    k_fuse<<<NTOT / 64, 256, 0, stream>>>(o1, o2, W_c1, b_c1, w_c2, out);
}